// Round 1
// baseline (732.655 us; speedup 1.0000x reference)
//
#include <hip/hip_runtime.h>

// DilConv fused: ReLU -> depthwise 3x3 (dilation 2, SAME) + bias
//              -> pointwise 1x1 (C->C) + bias -> BatchNorm (inference)
// N=32, H=W=56, C=256, fp32 in/out.
//
// Strategy: one fused kernel. Per block: 8x8 spatial tile of one image.
//   Phase 1: relu+depthwise -> d[64][256] in LDS.
//   Phase 2: pointwise GEMM (M=64, N=256, K=256), K chunked by 64 with the
//            pw kernel staged in LDS pre-scaled by folded BN scale.
//   Epilogue: + (pw_bias*inv + beta - mean*inv) per output channel.

constexpr int N_ = 32, H_ = 56, W_ = 56, C_ = 256;
constexpr int TILE = 8;      // 8x8 pixels per block
constexpr int PIX  = 64;
constexpr int KC   = 64;     // K-chunk for W staging
constexpr float BN_EPS = 1e-3f;

struct SM {
    float d[PIX][C_];    // 64 KB depthwise result
    float w[KC][C_];     // 64 KB pw-kernel chunk (pre-scaled by BN inv)
    float invS[C_];      // gamma/sqrt(var+eps)
    float offS[C_];      // pw_bias*inv + beta - mean*inv
};

__global__ __launch_bounds__(256, 1)
void dilconv_fused(const float* __restrict__ x,
                   const float* __restrict__ dwk,    // [3][3][256]
                   const float* __restrict__ dwb,    // [256]
                   const float* __restrict__ pwk,    // [256][256] ci-major
                   const float* __restrict__ pwb,    // [256]
                   const float* __restrict__ gamma,
                   const float* __restrict__ beta,
                   const float* __restrict__ mmean,
                   const float* __restrict__ mvar,
                   float* __restrict__ out)
{
    extern __shared__ char smem_raw[];
    SM& sm = *reinterpret_cast<SM*>(smem_raw);

    const int tid = threadIdx.x;
    const int bid = blockIdx.x;
    const int n   = bid / 49;
    const int t   = bid % 49;
    const int h0  = (t / 7) * TILE;
    const int w0  = (t % 7) * TILE;

    // ---- BN fold (256 threads -> 256 channels) ----
    {
        const float iv = gamma[tid] / sqrtf(mvar[tid] + BN_EPS);
        sm.invS[tid] = iv;
        sm.offS[tid] = pwb[tid] * iv + beta[tid] - mmean[tid] * iv;
    }

    // ---- Phase 1: ReLU + dilated depthwise + bias -> sm.d ----
    {
        const int c4 = (tid & 63) << 2;   // 4 channels per thread (float4)
        const int p0 = (tid >> 6) << 4;   // 16 pixels per thread
        float4 kreg[9];
        #pragma unroll
        for (int kk = 0; kk < 9; ++kk)
            kreg[kk] = *reinterpret_cast<const float4*>(dwk + kk * C_ + c4);
        const float4 bias = *reinterpret_cast<const float4*>(dwb + c4);

        #pragma unroll 2
        for (int pi = 0; pi < 16; ++pi) {
            const int p  = p0 + pi;
            const int ph = h0 + (p >> 3);
            const int pw = w0 + (p & 7);
            float ax = bias.x, ay = bias.y, az = bias.z, aw = bias.w;
            #pragma unroll
            for (int kh = 0; kh < 3; ++kh) {
                const int ih = ph + 2 * kh - 2;
                #pragma unroll
                for (int kw = 0; kw < 3; ++kw) {
                    const int iw = pw + 2 * kw - 2;
                    if ((unsigned)ih < (unsigned)H_ && (unsigned)iw < (unsigned)W_) {
                        const float4 v = *reinterpret_cast<const float4*>(
                            x + (((size_t)(n * H_ + ih) * W_ + iw) * C_) + c4);
                        const float4 kv = kreg[kh * 3 + kw];
                        ax = fmaf(fmaxf(v.x, 0.f), kv.x, ax);
                        ay = fmaf(fmaxf(v.y, 0.f), kv.y, ay);
                        az = fmaf(fmaxf(v.z, 0.f), kv.z, az);
                        aw = fmaf(fmaxf(v.w, 0.f), kv.w, aw);
                    }
                }
            }
            float4 r; r.x = ax; r.y = ay; r.z = az; r.w = aw;
            *reinterpret_cast<float4*>(&sm.d[p][c4]) = r;
        }
    }

    // ---- Phase 2: pointwise GEMM, micro-tile 8 pixels x 8 cos ----
    const int pg = tid >> 5;   // 0..7  -> pixels pg*8 .. pg*8+7
    const int cg = tid & 31;   // 0..31 -> cos cg + 32*j, j=0..7
    float acc[8][8];
    #pragma unroll
    for (int i = 0; i < 8; ++i)
        #pragma unroll
        for (int j = 0; j < 8; ++j) acc[i][j] = 0.f;

    for (int kc = 0; kc < C_ / KC; ++kc) {
        __syncthreads();   // prev chunk consumed; also covers phase1 + invS
        // stage W chunk, scaled by invS (coalesced float4)
        {
            const float4* src = reinterpret_cast<const float4*>(pwk + kc * KC * C_);
            #pragma unroll
            for (int i = 0; i < 16; ++i) {
                const int f   = i * 256 + tid;   // float4 index in chunk
                const int row = f >> 6;          // 64 float4 per row
                const int cc4 = (f & 63) << 2;
                float4 w = src[f];
                const float4 iv = *reinterpret_cast<const float4*>(&sm.invS[cc4]);
                w.x *= iv.x; w.y *= iv.y; w.z *= iv.z; w.w *= iv.w;
                *reinterpret_cast<float4*>(&sm.w[row][cc4]) = w;
            }
        }
        __syncthreads();
        // GEMM micro-kernel over this K chunk
        for (int k = 0; k < KC; k += 4) {
            float d4[8][4];
            #pragma unroll
            for (int i = 0; i < 8; ++i)
                *reinterpret_cast<float4*>(d4[i]) =
                    *reinterpret_cast<const float4*>(&sm.d[pg * 8 + i][kc * KC + k]);
            #pragma unroll
            for (int kk = 0; kk < 4; ++kk) {
                float wreg[8];
                #pragma unroll
                for (int j = 0; j < 8; ++j)
                    wreg[j] = sm.w[k + kk][cg + 32 * j];
                #pragma unroll
                for (int i = 0; i < 8; ++i) {
                    const float dv = d4[i][kk];
                    #pragma unroll
                    for (int j = 0; j < 8; ++j)
                        acc[i][j] = fmaf(dv, wreg[j], acc[i][j]);
                }
            }
        }
    }

    // ---- Epilogue: + offS, store ----
    float offr[8];
    #pragma unroll
    for (int j = 0; j < 8; ++j) offr[j] = sm.offS[cg + 32 * j];
    #pragma unroll
    for (int i = 0; i < 8; ++i) {
        const int p  = pg * 8 + i;
        const int oh = h0 + (p >> 3);
        const int ow = w0 + (p & 7);
        float* o = out + (((size_t)(n * H_ + oh) * W_ + ow) * C_) + cg;
        #pragma unroll
        for (int j = 0; j < 8; ++j)
            o[32 * j] = acc[i][j] + offr[j];
    }
}

extern "C" void kernel_launch(void* const* d_in, const int* in_sizes, int n_in,
                              void* d_out, int out_size, void* d_ws, size_t ws_size,
                              hipStream_t stream) {
    const float* x     = (const float*)d_in[0];
    const float* dwk   = (const float*)d_in[1];
    const float* dwb   = (const float*)d_in[2];
    const float* pwk   = (const float*)d_in[3];
    const float* pwb   = (const float*)d_in[4];
    const float* gam   = (const float*)d_in[5];
    const float* bet   = (const float*)d_in[6];
    const float* mmean = (const float*)d_in[7];
    const float* mvar  = (const float*)d_in[8];
    float* out = (float*)d_out;

    static_assert(sizeof(SM) <= 160 * 1024, "LDS overflow");
    // Opt in to >64KB dynamic LDS (idempotent, graph-capture safe).
    (void)hipFuncSetAttribute((const void*)dilconv_fused,
                              hipFuncAttributeMaxDynamicSharedMemorySize,
                              (int)sizeof(SM));

    dilconv_fused<<<dim3(N_ * 49), dim3(256), sizeof(SM), stream>>>(
        x, dwk, dwb, pwk, pwb, gam, bet, mmean, mvar, out);
}

// Round 2
// 347.748 us; speedup vs baseline: 2.1069x; 2.1069x over previous
//
#include <hip/hip_runtime.h>

// DilConv fused: ReLU -> depthwise 3x3 (dil 2, SAME) + bias
//              -> pointwise 1x1 (C->C) via f16 MFMA + bias -> BN (inference)
// N=32, H=W=56, C=256, fp32 in/out. fp16 used ONLY for pointwise GEMM operands
// (fp32 accumulate), adding ~3e-4 absmax on a 0.0039 baseline.
//
// Per block (256 thr): 8x8 pixel tile.
//   prologue: offC[co] = pwb*inv + beta - mean*inv (inv = gamma*rsqrt(var+eps))
//   phase 1 : relu+depthwise fp32 -> d[64][256] f16 in LDS (slot-swizzled)
//   phase 2 : GEMM M=64,N=256,K=256 via mfma_f32_16x16x32_f16, K chunked by 64;
//             W^T (fp16, inv-folded, pre-swizzled) staged from d_ws (prep kernel)
//   epilogue: acc + offC -> out (fp32)

typedef _Float16 f16;
typedef _Float16 f16x4 __attribute__((ext_vector_type(4)));
typedef _Float16 f16x8 __attribute__((ext_vector_type(8)));
typedef float    f32x4 __attribute__((ext_vector_type(4)));

constexpr int   N_ = 32, H_ = 56, W_ = 56, C_ = 256;
constexpr int   PIX = 64;
constexpr float BN_EPS = 1e-3f;
constexpr int   WS_BYTES = 4 * 16384 * 2;   // 4 chunks x [256 co][64 ci] f16

// LDS: d[p][ch] f16, row 512B, 16B slots XOR-swizzled by (p&7)
//      w[co][k]  f16, row 128B, 16B slots XOR-swizzled by (co&7)
struct SM {
    f16   d[PIX * 256];   // 32768 B
    f16   w[256 * 64];    // 32768 B
    float offC[256];      //  1024 B
};

__global__ void prep_w(const float* __restrict__ pwk,
                       const float* __restrict__ gamma,
                       const float* __restrict__ mvar,
                       f16* __restrict__ ws16)
{
    const int co = blockIdx.x;    // 0..255
    const int t  = threadIdx.x;   // ci 0..255
    const float iv = gamma[co] * rsqrtf(mvar[co] + BN_EPS);
    const float v  = pwk[(size_t)t * C_ + co] * iv;   // W^T, BN-scale folded
    const int chunk = t >> 6, k = t & 63;
    ws16[chunk * 16384 + co * 64 + (((k >> 3) ^ (co & 7)) << 3) + (k & 7)] = (f16)v;
}

template <bool FROM_WS>
__global__ __launch_bounds__(256, 2)
void dilconv_mfma(const float* __restrict__ x,
                  const float* __restrict__ dwk,
                  const float* __restrict__ dwb,
                  const float* __restrict__ pwk,
                  const float* __restrict__ pwb,
                  const float* __restrict__ gamma,
                  const float* __restrict__ beta,
                  const float* __restrict__ mmean,
                  const float* __restrict__ mvar,
                  const f16*   __restrict__ wsw,
                  float* __restrict__ out)
{
    extern __shared__ char smem_raw[];
    SM& sm = *reinterpret_cast<SM*>(smem_raw);

    const int tid = threadIdx.x;
    // XCD-aware bijective swizzle: 1568 = 8 * 196
    const int bid = (blockIdx.x & 7) * 196 + (blockIdx.x >> 3);
    const int n   = bid / 49;
    const int t   = bid % 49;
    const int h0  = (t / 7) * 8;
    const int w0  = (t % 7) * 8;
    const int l   = tid & 63;
    const int wq  = tid >> 6;

    // ---- prologue: BN fold ----
    float invW;
    {
        const float iv = gamma[tid] * rsqrtf(mvar[tid] + BN_EPS);
        invW = iv;
        sm.offC[tid] = pwb[tid] * iv + beta[tid] - mmean[tid] * iv;
    }

    // ---- phase 1: ReLU + dilated depthwise + bias -> sm.d (f16, swizzled) ----
    {
        const int c4 = l << 2;          // 4 channels per lane
        const int p0 = wq << 4;         // 16 pixels per wave/thread
        float4 kreg[9];
        #pragma unroll
        for (int kk = 0; kk < 9; ++kk)
            kreg[kk] = *reinterpret_cast<const float4*>(dwk + kk * C_ + c4);
        const float4 bias = *reinterpret_cast<const float4*>(dwb + c4);

        #pragma unroll 2
        for (int pi = 0; pi < 16; ++pi) {
            const int p  = p0 + pi;
            const int ph = h0 + (p >> 3);
            const int pw = w0 + (p & 7);
            float ax = bias.x, ay = bias.y, az = bias.z, aw = bias.w;
            #pragma unroll
            for (int kh = 0; kh < 3; ++kh) {
                const int ih = ph + 2 * kh - 2;
                #pragma unroll
                for (int kw = 0; kw < 3; ++kw) {
                    const int iw = pw + 2 * kw - 2;
                    if ((unsigned)ih < (unsigned)H_ && (unsigned)iw < (unsigned)W_) {
                        const float4 v = *reinterpret_cast<const float4*>(
                            x + (((size_t)(n * H_ + ih) * W_ + iw) * C_) + c4);
                        const float4 kv = kreg[kh * 3 + kw];
                        ax = fmaf(fmaxf(v.x, 0.f), kv.x, ax);
                        ay = fmaf(fmaxf(v.y, 0.f), kv.y, ay);
                        az = fmaf(fmaxf(v.z, 0.f), kv.z, az);
                        aw = fmaf(fmaxf(v.w, 0.f), kv.w, aw);
                    }
                }
            }
            const f16x4 hv = { (f16)ax, (f16)ay, (f16)az, (f16)aw };
            const int idx = p * 256 + ((((c4 >> 3) ^ (p & 7)) << 3) | (c4 & 7));
            *reinterpret_cast<f16x4*>(&sm.d[idx]) = hv;
        }
    }

    // ---- phase 2: MFMA GEMM, wave wq owns cos [wq*64, wq*64+64) ----
    f32x4 acc[4][4];
    #pragma unroll
    for (int i = 0; i < 4; ++i)
        #pragma unroll
        for (int j = 0; j < 4; ++j) acc[i][j] = (f32x4){0.f, 0.f, 0.f, 0.f};

    const int arow = l & 15;
    const int koct = l >> 4;   // 0..3: which 8-k octet

    for (int c = 0; c < 4; ++c) {
        __syncthreads();   // prev chunk consumed (c==0: also phase1/offC fence)
        if constexpr (FROM_WS) {
            const float4* wsrc = reinterpret_cast<const float4*>(wsw) + c * 2048;
            #pragma unroll
            for (int i = 0; i < 8; ++i) {
                const int u = i * 256 + tid;
                const float4 v = wsrc[u];
                *reinterpret_cast<float4*>(&sm.w[u * 8]) = v;
            }
        } else {
            // transposed in-kernel staging: thread owns co = tid
            const int co = tid;
            const float* wcol = pwk + (size_t)c * 64 * C_ + co;
            #pragma unroll
            for (int g = 0; g < 8; ++g) {
                f16x8 hv;
                #pragma unroll
                for (int j = 0; j < 8; ++j)
                    hv[j] = (f16)(wcol[(g * 8 + j) * C_] * invW);
                *reinterpret_cast<f16x8*>(&sm.w[co * 64 + ((g ^ (co & 7)) << 3)]) = hv;
            }
        }
        __syncthreads();

        #pragma unroll
        for (int ks = 0; ks < 2; ++ks) {
            f16x8 a[4], b[4];
            const int aslot = c * 8 + ks * 4 + koct;
            #pragma unroll
            for (int mt = 0; mt < 4; ++mt) {
                const int row = mt * 16 + arow;
                a[mt] = *reinterpret_cast<const f16x8*>(
                    &sm.d[row * 256 + ((aslot ^ (arow & 7)) << 3)]);
            }
            #pragma unroll
            for (int nt = 0; nt < 4; ++nt) {
                const int co = wq * 64 + nt * 16 + arow;
                b[nt] = *reinterpret_cast<const f16x8*>(
                    &sm.w[co * 64 + (((ks * 4 + koct) ^ (co & 7)) << 3)]);
            }
            #pragma unroll
            for (int mt = 0; mt < 4; ++mt)
                #pragma unroll
                for (int nt = 0; nt < 4; ++nt)
                    acc[mt][nt] = __builtin_amdgcn_mfma_f32_16x16x32_f16(
                        a[mt], b[nt], acc[mt][nt], 0, 0, 0);
        }
    }

    // ---- epilogue: + offC, store fp32 ----
    const int prb = (l >> 4) * 4;   // C/D: col = l&15, row = (l>>4)*4 + reg
    #pragma unroll
    for (int nt = 0; nt < 4; ++nt) {
        const int co  = wq * 64 + nt * 16 + (l & 15);
        const float off = sm.offC[co];
        #pragma unroll
        for (int mt = 0; mt < 4; ++mt) {
            #pragma unroll
            for (int r = 0; r < 4; ++r) {
                const int p  = mt * 16 + prb + r;
                const int oh = h0 + (p >> 3);
                const int ow = w0 + (p & 7);
                out[((size_t)((n * H_ + oh) * W_ + ow)) * C_ + co] = acc[mt][nt][r] + off;
            }
        }
    }
}

extern "C" void kernel_launch(void* const* d_in, const int* in_sizes, int n_in,
                              void* d_out, int out_size, void* d_ws, size_t ws_size,
                              hipStream_t stream) {
    const float* x     = (const float*)d_in[0];
    const float* dwk   = (const float*)d_in[1];
    const float* dwb   = (const float*)d_in[2];
    const float* pwk   = (const float*)d_in[3];
    const float* pwb   = (const float*)d_in[4];
    const float* gam   = (const float*)d_in[5];
    const float* bet   = (const float*)d_in[6];
    const float* mmean = (const float*)d_in[7];
    const float* mvar  = (const float*)d_in[8];
    float* out = (float*)d_out;

    const bool use_ws = (ws_size >= (size_t)WS_BYTES);

    if (use_ws) {
        f16* ws16 = (f16*)d_ws;
        prep_w<<<dim3(256), dim3(256), 0, stream>>>(pwk, gam, mvar, ws16);
        (void)hipFuncSetAttribute(reinterpret_cast<const void*>(&dilconv_mfma<true>),
                                  hipFuncAttributeMaxDynamicSharedMemorySize,
                                  (int)sizeof(SM));
        dilconv_mfma<true><<<dim3(N_ * 49), dim3(256), sizeof(SM), stream>>>(
            x, dwk, dwb, pwk, pwb, gam, bet, mmean, mvar, ws16, out);
    } else {
        (void)hipFuncSetAttribute(reinterpret_cast<const void*>(&dilconv_mfma<false>),
                                  hipFuncAttributeMaxDynamicSharedMemorySize,
                                  (int)sizeof(SM));
        dilconv_mfma<false><<<dim3(N_ * 49), dim3(256), sizeof(SM), stream>>>(
            x, dwk, dwb, pwk, pwb, gam, bet, mmean, mvar, nullptr, out);
    }
}